// Round 15
// baseline (419.848 us; speedup 1.0000x reference)
//
#include <hip/hip_runtime.h>

#define KSEL 52

using frag_ab = __attribute__((ext_vector_type(8))) short;  // 8 bf16
using frag_cd = __attribute__((ext_vector_type(4))) float;  // 4 fp32

__device__ __forceinline__ float bf2f(ushort u) {
    union { uint i; float f; } c; c.i = ((uint)u) << 16; return c.f;
}
__device__ __forceinline__ ushort f2bf(float f) {
    uint x = __builtin_bit_cast(uint, f);
    return (ushort)((x + 0x7FFFu + ((x >> 16) & 1u)) >> 16);
}
__device__ __forceinline__ void splitbf(float v, ushort& hi, ushort& lo) {
    hi = f2bf(v);
    lo = f2bf(v - bf2f(hi));
}

// ---------------------------------------------------------------------------
// k_setup: fused weight prep (W1/W2 -> hi/lo MFMA B-frag planes) + norm
// (scalars + w2tw). Blocks 0..383 = prep; block 384 = norm.
// ---------------------------------------------------------------------------
__global__ __launch_bounds__(256) void k_setup(const float* __restrict__ W1,
                                               const float* __restrict__ W2,
                                               const float* __restrict__ tw,
                                               const float* __restrict__ b2,
                                               ushort* __restrict__ w1h, ushort* __restrict__ w1l,
                                               ushort* __restrict__ w2h, ushort* __restrict__ w2l,
                                               float* __restrict__ scalars,
                                               float* __restrict__ w2tw) {
    int b = blockIdx.x;
    if (b < 384) {
        int id = b * 256 + threadIdx.x;
        if (id < 32768) {
            int j = id & 7, l = (id >> 3) & 63, nt = (id >> 9) & 15, kt = id >> 13;
            float v = W1[(kt*32 + ((l >> 4) << 3) + j) * 256 + nt*16 + (l & 15)];
            ushort h, o; splitbf(v, h, o);
            w1h[id] = h; w1l[id] = o;
        } else {
            int id2 = id - 32768;  // < 65536
            int j = id2 & 7, l = (id2 >> 3) & 63, nt = (id2 >> 9) & 15, kt = id2 >> 13;
            float v = W2[(kt*32 + ((l >> 4) << 3) + j) * 256 + nt*16 + (l & 15)];
            ushort h, o; splitbf(v, h, o);
            w2h[id2] = h; w2l[id2] = o;
        }
    } else {
        int t = threadIdx.x;
        __shared__ float twl[256];
        __shared__ float red[256];
        twl[t] = tw[t];
        __syncthreads();
        float s = 0.f;
        const float* row = W2 + (size_t)t * 256;
#pragma unroll 4
        for (int n = 0; n < 256; ++n) s += row[n] * twl[n];
        w2tw[t] = s;
        red[t] = twl[t] * twl[t];
        __syncthreads();
        for (int off = 128; off > 0; off >>= 1) {
            if (t < off) red[t] += red[t + off];
            __syncthreads();
        }
        float nrm = red[0];
        __syncthreads();
        red[t] = b2[t] * twl[t];
        __syncthreads();
        for (int off = 128; off > 0; off >>= 1) {
            if (t < off) red[t] += red[t + off];
            __syncthreads();
        }
        if (t == 0) { scalars[0] = rsqrtf(nrm); scalars[1] = red[0]; }
    }
}

// ---------------------------------------------------------------------------
// k_prep2: transpose fcw [256 out][512 in] -> fcwT [512 in][256 out] (fp32).
// Runs after k_stats; fcwT lives in the (then-dead) `partial` buffer.
// ---------------------------------------------------------------------------
__global__ __launch_bounds__(256) void k_prep2(const float* __restrict__ fcw,
                                               float* __restrict__ fcwT) {
    int id = blockIdx.x * 256 + threadIdx.x;   // < 131072
    int k = id & 511, j = id >> 9;
    fcwT[(size_t)k * 256 + j] = fcw[(size_t)j * 512 + k];
}

// ---------------------------------------------------------------------------
// Common body for k_conv variants. STORE_H1 = 0: store h0 hi/lo planes.
// STORE_H1 = 1: store h1 = acc+b1 as packed hi|lo<<16 uint (main path).
// Embedding gather: wave-uniform scalar token loads; 2 nodes interleaved
// per iteration for 2x memory-level parallelism (bit-identical per node).
// ---------------------------------------------------------------------------
template <int STORE_H1>
__device__ __forceinline__ void conv_body(const int* __restrict__ tokens,
                                          const int* __restrict__ ntype,
                                          const float* __restrict__ st,
                                          const float* __restrict__ nte,
                                          const int* __restrict__ esrc,
                                          const int* __restrict__ edst,
                                          const ushort* __restrict__ w1h,
                                          const ushort* __restrict__ w1l,
                                          const float* __restrict__ b1,
                                          ushort* __restrict__ h0hi,
                                          ushort* __restrict__ h0lo,
                                          uint* __restrict__ h1p,
                                          float* __restrict__ partial) {
    __shared__ __align__(16) float xf[64 * 132];     // 33792 B fp32 x tile (pad 4)
    __shared__ int ecnt[64], eoff[64], epos[64];     // 768 B
    __shared__ int esort[256];                       // 1024 B src ids, dst-sorted
    __shared__ float rsum[256], rsq[256];            // 2048 B
    int tid = threadIdx.x, g = blockIdx.x;
    int w = tid >> 6, l = tid & 63;

    if (tid < 64) ecnt[tid] = 0;
    rsum[tid] = 0.f; rsq[tid] = 0.f;
    int my_src, my_dst;
    {
        int e = g * 256 + tid;
        my_src = esrc[e] - g * 64;
        my_dst = edst[e] - g * 64;
    }

    // embedding: wave w computes nodes [w*16, w*16+16); lane owns channels (2l, 2l+1)
    {
        int gnu = __builtin_amdgcn_readfirstlane((g * 64 + w * 16) * 16);
        for (int i = 0; i < 16; i += 2) {
            const int* tp0 = tokens + gnu + i * 16;
            const int* tp1 = tp0 + 16;
            float a0 = 0.f, a1 = 0.f, c0 = 0.f, c1 = 0.f;
            int cnt0 = 0, cnt1 = 0;
#pragma unroll
            for (int t = 0; t < 16; ++t) {
                int tok0 = tp0[t];               // wave-uniform -> s_load
                int tok1 = tp1[t];
                cnt0 += (tok0 != 0);
                cnt1 += (tok1 != 0);
                float2 v0 = *(const float2*)(st + (size_t)tok0 * 128 + 2 * l);
                float2 v1 = *(const float2*)(st + (size_t)tok1 * 128 + 2 * l);
                a0 += v0.x; a1 += v0.y;
                c0 += v1.x; c1 += v1.y;
            }
            int node0 = w * 16 + i, node1 = node0 + 1;
            float inv0 = 1.0f / (float)(cnt0 > 0 ? cnt0 : 1);
            float inv1 = 1.0f / (float)(cnt1 > 0 ? cnt1 : 1);
            float2 nv0 = *(const float2*)(nte + (size_t)ntype[g * 64 + node0] * 128 + 2 * l);
            float2 nv1 = *(const float2*)(nte + (size_t)ntype[g * 64 + node1] * 128 + 2 * l);
            float2 o0; o0.x = a0 * inv0 + nv0.x; o0.y = a1 * inv0 + nv0.y;
            float2 o1; o1.x = c0 * inv1 + nv1.x; o1.y = c1 * inv1 + nv1.y;
            *(float2*)(&xf[node0 * 132 + 2 * l]) = o0;
            *(float2*)(&xf[node1 * 132 + 2 * l]) = o1;
        }
    }
    __syncthreads();   // xf ready; ecnt zeros visible

    // counting sort of edges by dst
    atomicAdd(&ecnt[my_dst], 1);
    __syncthreads();
    if (tid < 64) {
        int v = ecnt[tid];
        int p = v;
#pragma unroll
        for (int m = 1; m < 64; m <<= 1) {
            int u = __shfl_up(p, m, 64);
            if (tid >= m) p += u;
        }
        eoff[tid] = p - v;
        epos[tid] = p - v;
    }
    __syncthreads();
    {
        int pos = atomicAdd(&epos[my_dst], 1);
        esort[pos] = my_src;
    }
    __syncthreads();

    // aggregation: race-free per-(dst,channel) accumulation
    float aggv[32];
    {
        int c = tid & 127, dbase = tid >> 7;
#pragma unroll 4
        for (int k = 0; k < 32; ++k) {
            int d = 2 * k + dbase;
            int e0 = eoff[d], e1 = e0 + ecnt[d];
            float s = 0.f;
            for (int e = e0; e < e1; ++e)
                s += fmaxf(xf[esort[e] * 132 + c], 0.f);
            aggv[k] = s;
        }
    }
    __syncthreads();   // all reads of x done before any write
    {
        int c = tid & 127, dbase = tid >> 7;
#pragma unroll
        for (int k = 0; k < 32; ++k)
            xf[(2 * k + dbase) * 132 + c] += aggv[k];
    }
    __syncthreads();

    if (!STORE_H1) {
        // store h0 as hi/lo bf16 planes (coalesced 16B stores)
#pragma unroll
        for (int it = 0; it < 4; ++it) {
            int G = it * 256 + tid;
            int i = G >> 4, cg = G & 15;
            const float* src = &xf[i * 132 + cg * 8];
            ushort h[8], o[8];
#pragma unroll
            for (int j = 0; j < 8; ++j) splitbf(src[j], h[j], o[j]);
            uint4 ph, pl;
            ph.x = (uint)h[0] | ((uint)h[1] << 16); ph.y = (uint)h[2] | ((uint)h[3] << 16);
            ph.z = (uint)h[4] | ((uint)h[5] << 16); ph.w = (uint)h[6] | ((uint)h[7] << 16);
            pl.x = (uint)o[0] | ((uint)o[1] << 16); pl.y = (uint)o[2] | ((uint)o[3] << 16);
            pl.z = (uint)o[4] | ((uint)o[5] << 16); pl.w = (uint)o[6] | ((uint)o[7] << 16);
            size_t off = (size_t)(g * 64 + i) * 128 + cg * 8;
            *(uint4*)(h0hi + off) = ph;
            *(uint4*)(h0lo + off) = pl;
        }
    }

    // split MFMA GEMM1 -> BN partial sums (+ h1 store if STORE_H1)
    int lane = tid & 63;
    int quad = lane >> 4, l15 = lane & 15;
    frag_ab ah[4], al[4];
#pragma unroll
    for (int kt = 0; kt < 4; ++kt) {
        const float* p = &xf[(w * 16 + l15) * 132 + kt * 32 + quad * 8];
#pragma unroll
        for (int j = 0; j < 8; ++j) {
            ushort h, o; splitbf(p[j], h, o);
            ah[kt][j] = (short)h; al[kt][j] = (short)o;
        }
    }

    for (int nt = 0; nt < 16; ++nt) {
        frag_cd acc = {0.f, 0.f, 0.f, 0.f};
#pragma unroll
        for (int kt = 0; kt < 4; ++kt) {
            frag_ab bh = *(const frag_ab*)(w1h + ((kt * 16 + nt) * 64 + lane) * 8);
            frag_ab bl = *(const frag_ab*)(w1l + ((kt * 16 + nt) * 64 + lane) * 8);
            acc = __builtin_amdgcn_mfma_f32_16x16x32_bf16(ah[kt], bh, acc, 0, 0, 0);
            acc = __builtin_amdgcn_mfma_f32_16x16x32_bf16(al[kt], bh, acc, 0, 0, 0);
            acc = __builtin_amdgcn_mfma_f32_16x16x32_bf16(ah[kt], bl, acc, 0, 0, 0);
        }
        int c = nt * 16 + l15;
        float bias = b1[c];
        float s4 = 0.f, q4 = 0.f;
#pragma unroll
        for (int r = 0; r < 4; ++r) {
            float v = acc[r] + bias;
            s4 += v; q4 += v * v;
            if (STORE_H1) {
                ushort hh, oo; splitbf(v, hh, oo);
                h1p[(size_t)(g * 64 + w * 16 + quad * 4 + r) * 256 + c] =
                    (uint)hh | ((uint)oo << 16);
            }
        }
        s4 += __shfl_xor(s4, 16, 64); s4 += __shfl_xor(s4, 32, 64);
        q4 += __shfl_xor(q4, 16, 64); q4 += __shfl_xor(q4, 32, 64);
        if (lane < 16) { atomicAdd(&rsum[c], s4); atomicAdd(&rsq[c], q4); }
    }
    __syncthreads();
    partial[(size_t)g * 512 + tid]       = rsum[tid];
    partial[(size_t)g * 512 + 256 + tid] = rsq[tid];
}

__global__ __launch_bounds__(256, 4) void k_conv(const int* tokens, const int* ntype,
        const float* st, const float* nte, const int* esrc, const int* edst,
        const ushort* w1h, const ushort* w1l, const float* b1,
        ushort* h0hi, ushort* h0lo, float* partial) {
    conv_body<0>(tokens, ntype, st, nte, esrc, edst, w1h, w1l, b1, h0hi, h0lo, nullptr, partial);
}

__global__ __launch_bounds__(256, 4) void k_conv2(const int* tokens, const int* ntype,
        const float* st, const float* nte, const int* esrc, const int* edst,
        const ushort* w1h, const ushort* w1l, const float* b1,
        uint* h1p, float* partial) {
    conv_body<1>(tokens, ntype, st, nte, esrc, edst, w1h, w1l, b1, nullptr, nullptr, h1p, partial);
}

// ---------------------------------------------------------------------------
// k_stats: reduce BN partials -> folded scale/shift (fp32)
// ---------------------------------------------------------------------------
__global__ __launch_bounds__(256) void k_stats(const float* __restrict__ partial,
                                               const float* __restrict__ gamma_,
                                               const float* __restrict__ beta_,
                                               float* __restrict__ scale,
                                               float* __restrict__ shift) {
    int c = blockIdx.x, t = threadIdx.x;
    float s = 0.f, q = 0.f;
    for (int g = t; g < 2048; g += 256) {
        s += partial[(size_t)g * 512 + c];
        q += partial[(size_t)g * 512 + 256 + c];
    }
    __shared__ float rs[256], rq[256];
    rs[t] = s; rq[t] = q;
    __syncthreads();
    if (t < 64) {
        s = rs[t] + rs[t + 64] + rs[t + 128] + rs[t + 192];
        q = rq[t] + rq[t + 64] + rq[t + 128] + rq[t + 192];
#pragma unroll
        for (int m = 1; m < 64; m <<= 1) { s += __shfl_xor(s, m, 64); q += __shfl_xor(q, m, 64); }
        if (t == 0) {
            float mu  = s * (1.0f / 131072.0f);
            float var = fmaxf(q * (1.0f / 131072.0f) - mu * mu, 0.f);
            float sc  = gamma_[c] * rsqrtf(var + 1e-5f);
            scale[c] = sc;
            shift[c] = beta_[c] - mu * sc;
        }
    }
}

// ---------------------------------------------------------------------------
// k_final (fallback path): split GEMM1 recompute from h0 planes + score
// via w2tw -> top-52 -> single-plane GEMM2 with fused pooling -> FC (fcwT).
// ---------------------------------------------------------------------------
__global__ __launch_bounds__(256) void k_final(const ushort* __restrict__ h0hi,
                                               const ushort* __restrict__ h0lo,
                                               const ushort* __restrict__ w1h,
                                               const ushort* __restrict__ w1l,
                                               const ushort* __restrict__ w2h,
                                               const float* __restrict__ b1,
                                               const float* __restrict__ b2,
                                               const float* __restrict__ scale,
                                               const float* __restrict__ shift,
                                               const float* __restrict__ scalars,
                                               const float* __restrict__ w2tw,
                                               const float* __restrict__ fcwT,
                                               const float* __restrict__ fcb,
                                               float* __restrict__ out) {
    __shared__ __align__(16) ushort hhi[64 * 264];
    __shared__ __align__(16) float auxA[512];
    __shared__ float b2l[256], w2t[256];
    __shared__ float slds[64], gate[64];
    __shared__ int   sel[64];
    int tid = threadIdx.x, g = blockIdx.x;
    int w = tid >> 6, lane = tid & 63;
    int quad = lane >> 4, l15 = lane & 15;

    {
        float sc = scale[tid];
        auxA[tid]       = sc;
        auxA[256 + tid] = b1[tid] * sc + shift[tid];
        b2l[tid] = b2[tid];
        w2t[tid] = w2tw[tid];
    }
    __syncthreads();

    {
        frag_ab ah[4], al[4];
#pragma unroll
        for (int kt = 0; kt < 4; ++kt) {
            size_t base = (size_t)(g * 64 + w * 16 + l15) * 128 + kt * 32 + quad * 8;
            ah[kt] = *(const frag_ab*)(h0hi + base);
            al[kt] = *(const frag_ab*)(h0lo + base);
        }
        float pr[4] = {0.f, 0.f, 0.f, 0.f};
        for (int nt = 0; nt < 16; ++nt) {
            frag_cd acc = {0.f, 0.f, 0.f, 0.f};
#pragma unroll
            for (int kt = 0; kt < 4; ++kt) {
                frag_ab bh = *(const frag_ab*)(w1h + ((kt * 16 + nt) * 64 + lane) * 8);
                frag_ab bl = *(const frag_ab*)(w1l + ((kt * 16 + nt) * 64 + lane) * 8);
                acc = __builtin_amdgcn_mfma_f32_16x16x32_bf16(ah[kt], bh, acc, 0, 0, 0);
                acc = __builtin_amdgcn_mfma_f32_16x16x32_bf16(al[kt], bh, acc, 0, 0, 0);
                acc = __builtin_amdgcn_mfma_f32_16x16x32_bf16(ah[kt], bl, acc, 0, 0, 0);
            }
            int c = nt * 16 + l15;
            float sc = auxA[c], s2 = auxA[256 + c], wt = w2t[c];
#pragma unroll
            for (int r = 0; r < 4; ++r) {
                float v = fmaxf(acc[r] * sc + s2, 0.f);
                pr[r] += v * wt;
                uint h = (uint)f2bf(v);
                uint other = __shfl_xor(h, 1, 64);
                if ((l15 & 1) == 0) {
                    int idx = (w * 16 + quad * 4 + r) * 264 + c;
                    *(uint*)(&hhi[idx]) = h | (other << 16);
                }
            }
        }
#pragma unroll
        for (int r = 0; r < 4; ++r) {
            pr[r] += __shfl_xor(pr[r], 1, 64);
            pr[r] += __shfl_xor(pr[r], 2, 64);
            pr[r] += __shfl_xor(pr[r], 4, 64);
            pr[r] += __shfl_xor(pr[r], 8, 64);
        }
        if (l15 == 0) {
#pragma unroll
            for (int r = 0; r < 4; ++r) slds[w * 16 + quad * 4 + r] = pr[r];
        }
    }
    __syncthreads();

    const float invn = scalars[0], b2tw = scalars[1];
    if (tid < 64) {
        float s = slds[tid];
        int rank = 0;
        for (int j2 = 0; j2 < 64; ++j2) {
            float sj = slds[j2];
            rank += (sj > s) || (sj == s && j2 < tid);
        }
        int issel = rank < KSEL;
        sel[tid]  = issel;
        gate[tid] = issel ? tanhf((s + b2tw) * invn) : 0.f;
    }
    __syncthreads();

    {
        float gr[4][4]; int sr[4][4];
#pragma unroll
        for (int p = 0; p < 4; ++p)
#pragma unroll
            for (int r = 0; r < 4; ++r) {
                int row = p * 16 + quad * 4 + r;
                gr[p][r] = gate[row]; sr[p][r] = sel[row];
            }
        float lmax[4] = {-1.0e30f, -1.0e30f, -1.0e30f, -1.0e30f};
        float lsum[4] = {0.f, 0.f, 0.f, 0.f};
#pragma unroll
        for (int nt = 0; nt < 4; ++nt) {
            int ntg = w * 4 + nt;
            frag_cd acc[4];
#pragma unroll
            for (int p = 0; p < 4; ++p) acc[p] = (frag_cd){0.f, 0.f, 0.f, 0.f};
#pragma unroll
            for (int kt = 0; kt < 8; ++kt) {
                frag_ab bh = *(const frag_ab*)(w2h + ((kt * 16 + ntg) * 64 + lane) * 8);
#pragma unroll
                for (int p = 0; p < 4; ++p) {
                    int offa = (p * 16 + l15) * 264 + kt * 32 + quad * 8;
                    frag_ab a2h = *(const frag_ab*)(hhi + offa);
                    acc[p] = __builtin_amdgcn_mfma_f32_16x16x32_bf16(a2h, bh, acc[p], 0, 0, 0);
                }
            }
            int c = ntg * 16 + l15;
            float bias = b2l[c];
#pragma unroll
            for (int p = 0; p < 4; ++p)
#pragma unroll
                for (int r = 0; r < 4; ++r) {
                    if (sr[p][r]) {
                        float v = (acc[p][r] + bias) * gr[p][r];
                        lsum[nt] += v;
                        lmax[nt] = fmaxf(lmax[nt], v);
                    }
                }
        }
#pragma unroll
        for (int nt = 0; nt < 4; ++nt) {
            lsum[nt] += __shfl_xor(lsum[nt], 16, 64);
            lsum[nt] += __shfl_xor(lsum[nt], 32, 64);
            lmax[nt] = fmaxf(lmax[nt], __shfl_xor(lmax[nt], 16, 64));
            lmax[nt] = fmaxf(lmax[nt], __shfl_xor(lmax[nt], 32, 64));
        }
        __syncthreads();
        if (quad == 0) {
#pragma unroll
            for (int nt = 0; nt < 4; ++nt) {
                int c = (w * 4 + nt) * 16 + l15;
                auxA[c]       = lmax[nt];
                auxA[256 + c] = lsum[nt] * (1.0f / 52.0f);
            }
        }
    }
    __syncthreads();

    {
        float a0 = 0.f, a1 = 0.f, a2 = 0.f, a3 = 0.f;
#pragma unroll 4
        for (int k = 0; k < 512; k += 4) {
            a0 += fcwT[(size_t)(k + 0) * 256 + tid] * auxA[k + 0];
            a1 += fcwT[(size_t)(k + 1) * 256 + tid] * auxA[k + 1];
            a2 += fcwT[(size_t)(k + 2) * 256 + tid] * auxA[k + 2];
            a3 += fcwT[(size_t)(k + 3) * 256 + tid] * auxA[k + 3];
        }
        out[(size_t)g * 256 + tid] = fcb[tid] + ((a0 + a1) + (a2 + a3));
    }
}

// ---------------------------------------------------------------------------
// k_final2 (main path): no GEMM1. Phase A: quarter-wave scheme — iteration
// covers 4 rows (quad=row), lane covers 16 cols; score reduce = 4 shfls per
// 4 rows (16 total vs 96). Then top-52 -> GEMM2 with fused pooling -> FC.
// ---------------------------------------------------------------------------
__global__ __launch_bounds__(256) void k_final2(const uint* __restrict__ h1p,
                                                const ushort* __restrict__ w2h,
                                                const float* __restrict__ b2,
                                                const float* __restrict__ scale,
                                                const float* __restrict__ shift,
                                                const float* __restrict__ scalars,
                                                const float* __restrict__ w2tw,
                                                const float* __restrict__ fcwT,
                                                const float* __restrict__ fcb,
                                                float* __restrict__ out) {
    __shared__ __align__(16) ushort hhi[64 * 264];
    __shared__ __align__(16) float auxA[512];   // scale | shift ; later cat
    __shared__ float b2l[256], w2t[256];
    __shared__ float slds[64], gate[64];
    __shared__ int   sel[64];
    int tid = threadIdx.x, g = blockIdx.x;
    int w = tid >> 6, lane = tid & 63;
    int quad = lane >> 4, l15 = lane & 15;

    auxA[tid]       = scale[tid];
    auxA[256 + tid] = shift[tid];
    b2l[tid] = b2[tid];
    w2t[tid] = w2tw[tid];
    __syncthreads();

    // Phase A: iteration ii covers rows w*16 + ii*4 + quad; lane covers cols
    // [l15*16, l15*16+16). Score reduce across l15 only (4 shfls / 4 rows).
#pragma unroll
    for (int ii = 0; ii < 4; ++ii) {
        int row = w * 16 + ii * 4 + quad;
        const uint* hrow = h1p + (size_t)(g * 64 + row) * 256 + l15 * 16;
        float pr = 0.f;
        ushort hvv[16];
#pragma unroll
        for (int j = 0; j < 4; ++j) {
            uint4 u = *(const uint4*)(hrow + 4 * j);
            float4 sc4 = *(const float4*)(&auxA[l15 * 16 + 4 * j]);
            float4 sh4 = *(const float4*)(&auxA[256 + l15 * 16 + 4 * j]);
            float4 wt4 = *(const float4*)(&w2t[l15 * 16 + 4 * j]);
            uint us[4] = {u.x, u.y, u.z, u.w};
            float scs[4] = {sc4.x, sc4.y, sc4.z, sc4.w};
            float shs[4] = {sh4.x, sh4.y, sh4.z, sh4.w};
            float wts[4] = {wt4.x, wt4.y, wt4.z, wt4.w};
#pragma unroll
            for (int e = 0; e < 4; ++e) {
                float v = bf2f((ushort)(us[e] & 0xffffu)) + bf2f((ushort)(us[e] >> 16));
                float t = fmaxf(v * scs[e] + shs[e], 0.f);
                pr += t * wts[e];
                hvv[4 * j + e] = f2bf(t);
            }
        }
        uint o[8];
#pragma unroll
        for (int q2 = 0; q2 < 8; ++q2)
            o[q2] = (uint)hvv[2 * q2] | ((uint)hvv[2 * q2 + 1] << 16);
        uint4 o0; o0.x = o[0]; o0.y = o[1]; o0.z = o[2]; o0.w = o[3];
        uint4 o1; o1.x = o[4]; o1.y = o[5]; o1.z = o[6]; o1.w = o[7];
        *(uint4*)(&hhi[row * 264 + l15 * 16])     = o0;
        *(uint4*)(&hhi[row * 264 + l15 * 16 + 8]) = o1;
        pr += __shfl_xor(pr, 1, 64);
        pr += __shfl_xor(pr, 2, 64);
        pr += __shfl_xor(pr, 4, 64);
        pr += __shfl_xor(pr, 8, 64);
        if (l15 == 0) slds[row] = pr;
    }
    __syncthreads();

    const float invn = scalars[0], b2tw = scalars[1];
    if (tid < 64) {
        float s = slds[tid];
        int rank = 0;
        for (int j2 = 0; j2 < 64; ++j2) {
            float sj = slds[j2];
            rank += (sj > s) || (sj == s && j2 < tid);
        }
        int issel = rank < KSEL;
        sel[tid]  = issel;
        gate[tid] = issel ? tanhf((s + b2tw) * invn) : 0.f;
    }
    __syncthreads();

    // GEMM2 + fused pooling
    {
        float gr[4][4]; int sr[4][4];
#pragma unroll
        for (int p = 0; p < 4; ++p)
#pragma unroll
            for (int r = 0; r < 4; ++r) {
                int row = p * 16 + quad * 4 + r;
                gr[p][r] = gate[row]; sr[p][r] = sel[row];
            }
        float lmax[4] = {-1.0e30f, -1.0e30f, -1.0e30f, -1.0e30f};
        float lsum[4] = {0.f, 0.f, 0.f, 0.f};
#pragma unroll
        for (int nt = 0; nt < 4; ++nt) {
            int ntg = w * 4 + nt;
            frag_cd acc[4];
#pragma unroll
            for (int p = 0; p < 4; ++p) acc[p] = (frag_cd){0.f, 0.f, 0.f, 0.f};
#pragma unroll
            for (int kt = 0; kt < 8; ++kt) {
                frag_ab bh = *(const frag_ab*)(w2h + ((kt * 16 + ntg) * 64 + lane) * 8);
#pragma unroll
                for (int p = 0; p < 4; ++p) {
                    int offa = (p * 16 + l15) * 264 + kt * 32 + quad * 8;
                    frag_ab a2h = *(const frag_ab*)(hhi + offa);
                    acc[p] = __builtin_amdgcn_mfma_f32_16x16x32_bf16(a2h, bh, acc[p], 0, 0, 0);
                }
            }
            int c = ntg * 16 + l15;
            float bias = b2l[c];
#pragma unroll
            for (int p = 0; p < 4; ++p)
#pragma unroll
                for (int r = 0; r < 4; ++r) {
                    if (sr[p][r]) {
                        float v = (acc[p][r] + bias) * gr[p][r];
                        lsum[nt] += v;
                        lmax[nt] = fmaxf(lmax[nt], v);
                    }
                }
        }
#pragma unroll
        for (int nt = 0; nt < 4; ++nt) {
            lsum[nt] += __shfl_xor(lsum[nt], 16, 64);
            lsum[nt] += __shfl_xor(lsum[nt], 32, 64);
            lmax[nt] = fmaxf(lmax[nt], __shfl_xor(lmax[nt], 16, 64));
            lmax[nt] = fmaxf(lmax[nt], __shfl_xor(lmax[nt], 32, 64));
        }
        __syncthreads();
        if (quad == 0) {
#pragma unroll
            for (int nt = 0; nt < 4; ++nt) {
                int c = (w * 4 + nt) * 16 + l15;
                auxA[c]       = lmax[nt];
                auxA[256 + c] = lsum[nt] * (1.0f / 52.0f);
            }
        }
    }
    __syncthreads();

    // FC via transposed weights: coalesced dword loads, cat broadcast from LDS
    {
        float a0 = 0.f, a1 = 0.f, a2 = 0.f, a3 = 0.f;
#pragma unroll 4
        for (int k = 0; k < 512; k += 4) {
            a0 += fcwT[(size_t)(k + 0) * 256 + tid] * auxA[k + 0];
            a1 += fcwT[(size_t)(k + 1) * 256 + tid] * auxA[k + 1];
            a2 += fcwT[(size_t)(k + 2) * 256 + tid] * auxA[k + 2];
            a3 += fcwT[(size_t)(k + 3) * 256 + tid] * auxA[k + 3];
        }
        out[(size_t)g * 256 + tid] = fcb[tid] + ((a0 + a1) + (a2 + a3));
    }
}

// ---------------------------------------------------------------------------
extern "C" void kernel_launch(void* const* d_in, const int* in_sizes, int n_in,
                              void* d_out, int out_size, void* d_ws, size_t ws_size,
                              hipStream_t stream) {
    const int*   tokens = (const int*)d_in[0];
    const int*   ntype  = (const int*)d_in[1];
    const int*   eidx   = (const int*)d_in[2];
    const float* st     = (const float*)d_in[3];
    const float* nte    = (const float*)d_in[4];
    const float* W1     = (const float*)d_in[5];
    const float* b1     = (const float*)d_in[6];
    const float* gam    = (const float*)d_in[7];
    const float* bet    = (const float*)d_in[8];
    const float* W2     = (const float*)d_in[9];
    const float* b2     = (const float*)d_in[10];
    const float* tw     = (const float*)d_in[11];
    const float* fcw    = (const float*)d_in[12];
    const float* fcb    = (const float*)d_in[13];

    // shared small block (base of ws)
    char* ws = (char*)d_ws;
    ushort* w1h     = (ushort*)(ws);                 // 64 KB
    ushort* w1l     = (ushort*)(ws + 65536);         // 64 KB
    ushort* w2h     = (ushort*)(ws + 131072);        // 128 KB
    ushort* w2l     = (ushort*)(ws + 262144);        // 128 KB
    float*  scale   = (float*)(ws + 393216);         // 1 KB
    float*  shift   = (float*)(ws + 394240);         // 1 KB
    float*  scalars = (float*)(ws + 395264);         // 256 B
    float*  w2tw    = (float*)(ws + 395520);         // 1 KB
    float*  partial = (float*)(ws + 396544);         // 4 MB -> ends 4,590,848
    float*  fcwT    = partial;                       // 512 KB, reuses partial after k_stats
    char*   big     = ws + 4590848;

    const int* esrc = eidx;
    const int* edst = eidx + 524288;

    k_setup<<<385, 256, 0, stream>>>(W1, W2, tw, b2, w1h, w1l, w2h, w2l, scalars, w2tw);

    if (ws_size >= 4590848ull + 134217728ull) {
        // MAIN path: h1 (acc+b1) stored packed hi|lo bf16, 128 MB
        uint* h1p = (uint*)big;
        k_conv2<<<2048, 256, 0, stream>>>(tokens, ntype, st, nte, esrc, edst,
                                          w1h, w1l, b1, h1p, partial);
        k_stats<<<256,  256, 0, stream>>>(partial, gam, bet, scale, shift);
        k_prep2<<<512,  256, 0, stream>>>(fcw, fcwT);   // partial is dead now
        k_final2<<<2048, 256, 0, stream>>>(h1p, w2h, b2, scale, shift, scalars,
                                           w2tw, fcwT, fcb, (float*)d_out);
    } else {
        // FALLBACK path: h0 hi/lo planes, GEMM1 recompute in k_final
        ushort* h0hi = (ushort*)big;
        ushort* h0lo = (ushort*)(big + 33554432);
        k_conv <<<2048, 256, 0, stream>>>(tokens, ntype, st, nte, esrc, edst,
                                          w1h, w1l, b1, h0hi, h0lo, partial);
        k_stats<<<256,  256, 0, stream>>>(partial, gam, bet, scale, shift);
        k_prep2<<<512,  256, 0, stream>>>(fcw, fcwT);
        k_final<<<2048, 256, 0, stream>>>(h0hi, h0lo, w1h, w1l, w2h, b1, b2,
                                          scale, shift, scalars, w2tw, fcwT, fcb, (float*)d_out);
    }
}

// Round 16
// 392.259 us; speedup vs baseline: 1.0703x; 1.0703x over previous
//
#include <hip/hip_runtime.h>

#define KSEL 52

using frag_ab = __attribute__((ext_vector_type(8))) short;  // 8 bf16
using frag_cd = __attribute__((ext_vector_type(4))) float;  // 4 fp32

__device__ __forceinline__ float bf2f(ushort u) {
    union { uint i; float f; } c; c.i = ((uint)u) << 16; return c.f;
}
__device__ __forceinline__ ushort f2bf(float f) {
    uint x = __builtin_bit_cast(uint, f);
    return (ushort)((x + 0x7FFFu + ((x >> 16) & 1u)) >> 16);
}
__device__ __forceinline__ void splitbf(float v, ushort& hi, ushort& lo) {
    hi = f2bf(v);
    lo = f2bf(v - bf2f(hi));
}

// ---------------------------------------------------------------------------
// k_setup: fused weight prep (W1/W2 -> hi/lo MFMA B-frag planes) + norm
// (scalars + w2tw). Blocks 0..383 = prep; block 384 = norm.
// ---------------------------------------------------------------------------
__global__ __launch_bounds__(256) void k_setup(const float* __restrict__ W1,
                                               const float* __restrict__ W2,
                                               const float* __restrict__ tw,
                                               const float* __restrict__ b2,
                                               ushort* __restrict__ w1h, ushort* __restrict__ w1l,
                                               ushort* __restrict__ w2h, ushort* __restrict__ w2l,
                                               float* __restrict__ scalars,
                                               float* __restrict__ w2tw) {
    int b = blockIdx.x;
    if (b < 384) {
        int id = b * 256 + threadIdx.x;
        if (id < 32768) {
            int j = id & 7, l = (id >> 3) & 63, nt = (id >> 9) & 15, kt = id >> 13;
            float v = W1[(kt*32 + ((l >> 4) << 3) + j) * 256 + nt*16 + (l & 15)];
            ushort h, o; splitbf(v, h, o);
            w1h[id] = h; w1l[id] = o;
        } else {
            int id2 = id - 32768;  // < 65536
            int j = id2 & 7, l = (id2 >> 3) & 63, nt = (id2 >> 9) & 15, kt = id2 >> 13;
            float v = W2[(kt*32 + ((l >> 4) << 3) + j) * 256 + nt*16 + (l & 15)];
            ushort h, o; splitbf(v, h, o);
            w2h[id2] = h; w2l[id2] = o;
        }
    } else {
        int t = threadIdx.x;
        __shared__ float twl[256];
        __shared__ float red[256];
        twl[t] = tw[t];
        __syncthreads();
        float s = 0.f;
        const float* row = W2 + (size_t)t * 256;
#pragma unroll 4
        for (int n = 0; n < 256; ++n) s += row[n] * twl[n];
        w2tw[t] = s;
        red[t] = twl[t] * twl[t];
        __syncthreads();
        for (int off = 128; off > 0; off >>= 1) {
            if (t < off) red[t] += red[t + off];
            __syncthreads();
        }
        float nrm = red[0];
        __syncthreads();
        red[t] = b2[t] * twl[t];
        __syncthreads();
        for (int off = 128; off > 0; off >>= 1) {
            if (t < off) red[t] += red[t + off];
            __syncthreads();
        }
        if (t == 0) { scalars[0] = rsqrtf(nrm); scalars[1] = red[0]; }
    }
}

// ---------------------------------------------------------------------------
// k_prep2: transpose fcw [256 out][512 in] -> fcwT [512 in][256 out] (fp32).
// Runs after k_stats; fcwT lives in the (then-dead) `partial` buffer.
// ---------------------------------------------------------------------------
__global__ __launch_bounds__(256) void k_prep2(const float* __restrict__ fcw,
                                               float* __restrict__ fcwT) {
    int id = blockIdx.x * 256 + threadIdx.x;   // < 131072
    int k = id & 511, j = id >> 9;
    fcwT[(size_t)k * 256 + j] = fcw[(size_t)j * 512 + k];
}

// ---------------------------------------------------------------------------
// Common body for k_conv variants. STORE_H1 = 0: store h0 hi/lo planes.
// STORE_H1 = 1: store h1 = acc+b1 as packed hi|lo<<16 uint (main path).
// Embedding gather: R12 shfl-broadcast form (measured best: 183 us).
// ---------------------------------------------------------------------------
template <int STORE_H1>
__device__ __forceinline__ void conv_body(const int* __restrict__ tokens,
                                          const int* __restrict__ ntype,
                                          const float* __restrict__ st,
                                          const float* __restrict__ nte,
                                          const int* __restrict__ esrc,
                                          const int* __restrict__ edst,
                                          const ushort* __restrict__ w1h,
                                          const ushort* __restrict__ w1l,
                                          const float* __restrict__ b1,
                                          ushort* __restrict__ h0hi,
                                          ushort* __restrict__ h0lo,
                                          uint* __restrict__ h1p,
                                          float* __restrict__ partial) {
    __shared__ __align__(16) float xf[64 * 132];     // 33792 B fp32 x tile (pad 4)
    __shared__ int ecnt[64], eoff[64], epos[64];     // 768 B
    __shared__ int esort[256];                       // 1024 B src ids, dst-sorted
    __shared__ float rsum[256], rsq[256];            // 2048 B
    int tid = threadIdx.x, g = blockIdx.x;
    int w = tid >> 6, l = tid & 63;

    if (tid < 64) ecnt[tid] = 0;
    rsum[tid] = 0.f; rsq[tid] = 0.f;
    int my_src, my_dst;
    {
        int e = g * 256 + tid;
        my_src = esrc[e] - g * 64;
        my_dst = edst[e] - g * 64;
    }

    // embedding: wave w computes nodes [w*16, w*16+16); lane owns channels (2l, 2l+1)
    int myTok[16];
    {
        int base = (g * 64 + w * 16) * 16 + (l & 15);
#pragma unroll
        for (int i = 0; i < 16; ++i) myTok[i] = tokens[base + i * 16];
    }
    for (int i = 0; i < 16; ++i) {
        int node = w * 16 + i;
        int gn = g * 64 + node;
        int cnt = __popcll(__ballot(myTok[i] != 0) & 0xFFFFull);
        float a0 = 0.f, a1 = 0.f;
#pragma unroll
        for (int t = 0; t < 16; ++t) {
            int tok = __shfl(myTok[i], t, 64);
            float2 v = *(const float2*)(st + (size_t)tok * 128 + 2 * l);
            a0 += v.x; a1 += v.y;
        }
        float inv = 1.0f / (float)(cnt > 0 ? cnt : 1);
        a0 *= inv; a1 *= inv;
        float2 nv = *(const float2*)(nte + (size_t)ntype[gn] * 128 + 2 * l);
        float2 o; o.x = a0 + nv.x; o.y = a1 + nv.y;
        *(float2*)(&xf[node * 132 + 2 * l]) = o;
    }
    __syncthreads();   // xf ready; ecnt zeros visible

    // counting sort of edges by dst
    atomicAdd(&ecnt[my_dst], 1);
    __syncthreads();
    if (tid < 64) {
        int v = ecnt[tid];
        int p = v;
#pragma unroll
        for (int m = 1; m < 64; m <<= 1) {
            int u = __shfl_up(p, m, 64);
            if (tid >= m) p += u;
        }
        eoff[tid] = p - v;
        epos[tid] = p - v;
    }
    __syncthreads();
    {
        int pos = atomicAdd(&epos[my_dst], 1);
        esort[pos] = my_src;
    }
    __syncthreads();

    // aggregation: race-free per-(dst,channel) accumulation
    float aggv[32];
    {
        int c = tid & 127, dbase = tid >> 7;
#pragma unroll 4
        for (int k = 0; k < 32; ++k) {
            int d = 2 * k + dbase;
            int e0 = eoff[d], e1 = e0 + ecnt[d];
            float s = 0.f;
            for (int e = e0; e < e1; ++e)
                s += fmaxf(xf[esort[e] * 132 + c], 0.f);
            aggv[k] = s;
        }
    }
    __syncthreads();   // all reads of x done before any write
    {
        int c = tid & 127, dbase = tid >> 7;
#pragma unroll
        for (int k = 0; k < 32; ++k)
            xf[(2 * k + dbase) * 132 + c] += aggv[k];
    }
    __syncthreads();

    if (!STORE_H1) {
        // store h0 as hi/lo bf16 planes (coalesced 16B stores)
#pragma unroll
        for (int it = 0; it < 4; ++it) {
            int G = it * 256 + tid;
            int i = G >> 4, cg = G & 15;
            const float* src = &xf[i * 132 + cg * 8];
            ushort h[8], o[8];
#pragma unroll
            for (int j = 0; j < 8; ++j) splitbf(src[j], h[j], o[j]);
            uint4 ph, pl;
            ph.x = (uint)h[0] | ((uint)h[1] << 16); ph.y = (uint)h[2] | ((uint)h[3] << 16);
            ph.z = (uint)h[4] | ((uint)h[5] << 16); ph.w = (uint)h[6] | ((uint)h[7] << 16);
            pl.x = (uint)o[0] | ((uint)o[1] << 16); pl.y = (uint)o[2] | ((uint)o[3] << 16);
            pl.z = (uint)o[4] | ((uint)o[5] << 16); pl.w = (uint)o[6] | ((uint)o[7] << 16);
            size_t off = (size_t)(g * 64 + i) * 128 + cg * 8;
            *(uint4*)(h0hi + off) = ph;
            *(uint4*)(h0lo + off) = pl;
        }
    }

    // split MFMA GEMM1 -> BN partial sums (+ h1 store if STORE_H1)
    int lane = tid & 63;
    int quad = lane >> 4, l15 = lane & 15;
    frag_ab ah[4], al[4];
#pragma unroll
    for (int kt = 0; kt < 4; ++kt) {
        const float* p = &xf[(w * 16 + l15) * 132 + kt * 32 + quad * 8];
#pragma unroll
        for (int j = 0; j < 8; ++j) {
            ushort h, o; splitbf(p[j], h, o);
            ah[kt][j] = (short)h; al[kt][j] = (short)o;
        }
    }

    for (int nt = 0; nt < 16; ++nt) {
        frag_cd acc = {0.f, 0.f, 0.f, 0.f};
#pragma unroll
        for (int kt = 0; kt < 4; ++kt) {
            frag_ab bh = *(const frag_ab*)(w1h + ((kt * 16 + nt) * 64 + lane) * 8);
            frag_ab bl = *(const frag_ab*)(w1l + ((kt * 16 + nt) * 64 + lane) * 8);
            acc = __builtin_amdgcn_mfma_f32_16x16x32_bf16(ah[kt], bh, acc, 0, 0, 0);
            acc = __builtin_amdgcn_mfma_f32_16x16x32_bf16(al[kt], bh, acc, 0, 0, 0);
            acc = __builtin_amdgcn_mfma_f32_16x16x32_bf16(ah[kt], bl, acc, 0, 0, 0);
        }
        int c = nt * 16 + l15;
        float bias = b1[c];
        float s4 = 0.f, q4 = 0.f;
#pragma unroll
        for (int r = 0; r < 4; ++r) {
            float v = acc[r] + bias;
            s4 += v; q4 += v * v;
            if (STORE_H1) {
                ushort hh, oo; splitbf(v, hh, oo);
                h1p[(size_t)(g * 64 + w * 16 + quad * 4 + r) * 256 + c] =
                    (uint)hh | ((uint)oo << 16);
            }
        }
        s4 += __shfl_xor(s4, 16, 64); s4 += __shfl_xor(s4, 32, 64);
        q4 += __shfl_xor(q4, 16, 64); q4 += __shfl_xor(q4, 32, 64);
        if (lane < 16) { atomicAdd(&rsum[c], s4); atomicAdd(&rsq[c], q4); }
    }
    __syncthreads();
    partial[(size_t)g * 512 + tid]       = rsum[tid];
    partial[(size_t)g * 512 + 256 + tid] = rsq[tid];
}

__global__ __launch_bounds__(256, 4) void k_conv(const int* tokens, const int* ntype,
        const float* st, const float* nte, const int* esrc, const int* edst,
        const ushort* w1h, const ushort* w1l, const float* b1,
        ushort* h0hi, ushort* h0lo, float* partial) {
    conv_body<0>(tokens, ntype, st, nte, esrc, edst, w1h, w1l, b1, h0hi, h0lo, nullptr, partial);
}

__global__ __launch_bounds__(256, 4) void k_conv2(const int* tokens, const int* ntype,
        const float* st, const float* nte, const int* esrc, const int* edst,
        const ushort* w1h, const ushort* w1l, const float* b1,
        uint* h1p, float* partial) {
    conv_body<1>(tokens, ntype, st, nte, esrc, edst, w1h, w1l, b1, nullptr, nullptr, h1p, partial);
}

// ---------------------------------------------------------------------------
// k_stats: reduce BN partials -> folded scale/shift (fp32)
// ---------------------------------------------------------------------------
__global__ __launch_bounds__(256) void k_stats(const float* __restrict__ partial,
                                               const float* __restrict__ gamma_,
                                               const float* __restrict__ beta_,
                                               float* __restrict__ scale,
                                               float* __restrict__ shift) {
    int c = blockIdx.x, t = threadIdx.x;
    float s = 0.f, q = 0.f;
    for (int g = t; g < 2048; g += 256) {
        s += partial[(size_t)g * 512 + c];
        q += partial[(size_t)g * 512 + 256 + c];
    }
    __shared__ float rs[256], rq[256];
    rs[t] = s; rq[t] = q;
    __syncthreads();
    if (t < 64) {
        s = rs[t] + rs[t + 64] + rs[t + 128] + rs[t + 192];
        q = rq[t] + rq[t + 64] + rq[t + 128] + rq[t + 192];
#pragma unroll
        for (int m = 1; m < 64; m <<= 1) { s += __shfl_xor(s, m, 64); q += __shfl_xor(q, m, 64); }
        if (t == 0) {
            float mu  = s * (1.0f / 131072.0f);
            float var = fmaxf(q * (1.0f / 131072.0f) - mu * mu, 0.f);
            float sc  = gamma_[c] * rsqrtf(var + 1e-5f);
            scale[c] = sc;
            shift[c] = beta_[c] - mu * sc;
        }
    }
}

// ---------------------------------------------------------------------------
// k_final (fallback path): split GEMM1 recompute from h0 planes + score
// via w2tw -> top-52 -> single-plane GEMM2 with fused pooling -> FC (fcwT).
// ---------------------------------------------------------------------------
__global__ __launch_bounds__(256) void k_final(const ushort* __restrict__ h0hi,
                                               const ushort* __restrict__ h0lo,
                                               const ushort* __restrict__ w1h,
                                               const ushort* __restrict__ w1l,
                                               const ushort* __restrict__ w2h,
                                               const float* __restrict__ b1,
                                               const float* __restrict__ b2,
                                               const float* __restrict__ scale,
                                               const float* __restrict__ shift,
                                               const float* __restrict__ scalars,
                                               const float* __restrict__ w2tw,
                                               const float* __restrict__ fcwT,
                                               const float* __restrict__ fcb,
                                               float* __restrict__ out) {
    __shared__ __align__(16) ushort hhi[64 * 264];
    __shared__ __align__(16) float auxA[512];
    __shared__ float b2l[256], w2t[256];
    __shared__ float slds[64], gate[64];
    __shared__ int   sel[64];
    int tid = threadIdx.x, g = blockIdx.x;
    int w = tid >> 6, lane = tid & 63;
    int quad = lane >> 4, l15 = lane & 15;

    {
        float sc = scale[tid];
        auxA[tid]       = sc;
        auxA[256 + tid] = b1[tid] * sc + shift[tid];
        b2l[tid] = b2[tid];
        w2t[tid] = w2tw[tid];
    }
    __syncthreads();

    {
        frag_ab ah[4], al[4];
#pragma unroll
        for (int kt = 0; kt < 4; ++kt) {
            size_t base = (size_t)(g * 64 + w * 16 + l15) * 128 + kt * 32 + quad * 8;
            ah[kt] = *(const frag_ab*)(h0hi + base);
            al[kt] = *(const frag_ab*)(h0lo + base);
        }
        float pr[4] = {0.f, 0.f, 0.f, 0.f};
        for (int nt = 0; nt < 16; ++nt) {
            frag_cd acc = {0.f, 0.f, 0.f, 0.f};
#pragma unroll
            for (int kt = 0; kt < 4; ++kt) {
                frag_ab bh = *(const frag_ab*)(w1h + ((kt * 16 + nt) * 64 + lane) * 8);
                frag_ab bl = *(const frag_ab*)(w1l + ((kt * 16 + nt) * 64 + lane) * 8);
                acc = __builtin_amdgcn_mfma_f32_16x16x32_bf16(ah[kt], bh, acc, 0, 0, 0);
                acc = __builtin_amdgcn_mfma_f32_16x16x32_bf16(al[kt], bh, acc, 0, 0, 0);
                acc = __builtin_amdgcn_mfma_f32_16x16x32_bf16(ah[kt], bl, acc, 0, 0, 0);
            }
            int c = nt * 16 + l15;
            float sc = auxA[c], s2 = auxA[256 + c], wt = w2t[c];
#pragma unroll
            for (int r = 0; r < 4; ++r) {
                float v = fmaxf(acc[r] * sc + s2, 0.f);
                pr[r] += v * wt;
                uint h = (uint)f2bf(v);
                uint other = __shfl_xor(h, 1, 64);
                if ((l15 & 1) == 0) {
                    int idx = (w * 16 + quad * 4 + r) * 264 + c;
                    *(uint*)(&hhi[idx]) = h | (other << 16);
                }
            }
        }
#pragma unroll
        for (int r = 0; r < 4; ++r) {
            pr[r] += __shfl_xor(pr[r], 1, 64);
            pr[r] += __shfl_xor(pr[r], 2, 64);
            pr[r] += __shfl_xor(pr[r], 4, 64);
            pr[r] += __shfl_xor(pr[r], 8, 64);
        }
        if (l15 == 0) {
#pragma unroll
            for (int r = 0; r < 4; ++r) slds[w * 16 + quad * 4 + r] = pr[r];
        }
    }
    __syncthreads();

    const float invn = scalars[0], b2tw = scalars[1];
    if (tid < 64) {
        float s = slds[tid];
        int rank = 0;
        for (int j2 = 0; j2 < 64; ++j2) {
            float sj = slds[j2];
            rank += (sj > s) || (sj == s && j2 < tid);
        }
        int issel = rank < KSEL;
        sel[tid]  = issel;
        gate[tid] = issel ? tanhf((s + b2tw) * invn) : 0.f;
    }
    __syncthreads();

    {
        float gr[4][4]; int sr[4][4];
#pragma unroll
        for (int p = 0; p < 4; ++p)
#pragma unroll
            for (int r = 0; r < 4; ++r) {
                int row = p * 16 + quad * 4 + r;
                gr[p][r] = gate[row]; sr[p][r] = sel[row];
            }
        float lmax[4] = {-1.0e30f, -1.0e30f, -1.0e30f, -1.0e30f};
        float lsum[4] = {0.f, 0.f, 0.f, 0.f};
#pragma unroll
        for (int nt = 0; nt < 4; ++nt) {
            int ntg = w * 4 + nt;
            frag_cd acc[4];
#pragma unroll
            for (int p = 0; p < 4; ++p) acc[p] = (frag_cd){0.f, 0.f, 0.f, 0.f};
#pragma unroll
            for (int kt = 0; kt < 8; ++kt) {
                frag_ab bh = *(const frag_ab*)(w2h + ((kt * 16 + ntg) * 64 + lane) * 8);
#pragma unroll
                for (int p = 0; p < 4; ++p) {
                    int offa = (p * 16 + l15) * 264 + kt * 32 + quad * 8;
                    frag_ab a2h = *(const frag_ab*)(hhi + offa);
                    acc[p] = __builtin_amdgcn_mfma_f32_16x16x32_bf16(a2h, bh, acc[p], 0, 0, 0);
                }
            }
            int c = ntg * 16 + l15;
            float bias = b2l[c];
#pragma unroll
            for (int p = 0; p < 4; ++p)
#pragma unroll
                for (int r = 0; r < 4; ++r) {
                    if (sr[p][r]) {
                        float v = (acc[p][r] + bias) * gr[p][r];
                        lsum[nt] += v;
                        lmax[nt] = fmaxf(lmax[nt], v);
                    }
                }
        }
#pragma unroll
        for (int nt = 0; nt < 4; ++nt) {
            lsum[nt] += __shfl_xor(lsum[nt], 16, 64);
            lsum[nt] += __shfl_xor(lsum[nt], 32, 64);
            lmax[nt] = fmaxf(lmax[nt], __shfl_xor(lmax[nt], 16, 64));
            lmax[nt] = fmaxf(lmax[nt], __shfl_xor(lmax[nt], 32, 64));
        }
        __syncthreads();
        if (quad == 0) {
#pragma unroll
            for (int nt = 0; nt < 4; ++nt) {
                int c = (w * 4 + nt) * 16 + l15;
                auxA[c]       = lmax[nt];
                auxA[256 + c] = lsum[nt] * (1.0f / 52.0f);
            }
        }
    }
    __syncthreads();

    {
        float a0 = 0.f, a1 = 0.f, a2 = 0.f, a3 = 0.f;
#pragma unroll 4
        for (int k = 0; k < 512; k += 4) {
            a0 += fcwT[(size_t)(k + 0) * 256 + tid] * auxA[k + 0];
            a1 += fcwT[(size_t)(k + 1) * 256 + tid] * auxA[k + 1];
            a2 += fcwT[(size_t)(k + 2) * 256 + tid] * auxA[k + 2];
            a3 += fcwT[(size_t)(k + 3) * 256 + tid] * auxA[k + 3];
        }
        out[(size_t)g * 256 + tid] = fcb[tid] + ((a0 + a1) + (a2 + a3));
    }
}

// ---------------------------------------------------------------------------
// k_final2 (main path): no GEMM1. Phase A: quarter-wave scheme — iteration
// covers 4 rows (quad=row), lane covers 16 cols; score reduce = 4 shfls per
// 4 rows. Then top-52 -> GEMM2 with fused pooling -> FC.
// ---------------------------------------------------------------------------
__global__ __launch_bounds__(256) void k_final2(const uint* __restrict__ h1p,
                                                const ushort* __restrict__ w2h,
                                                const float* __restrict__ b2,
                                                const float* __restrict__ scale,
                                                const float* __restrict__ shift,
                                                const float* __restrict__ scalars,
                                                const float* __restrict__ w2tw,
                                                const float* __restrict__ fcwT,
                                                const float* __restrict__ fcb,
                                                float* __restrict__ out) {
    __shared__ __align__(16) ushort hhi[64 * 264];
    __shared__ __align__(16) float auxA[512];   // scale | shift ; later cat
    __shared__ float b2l[256], w2t[256];
    __shared__ float slds[64], gate[64];
    __shared__ int   sel[64];
    int tid = threadIdx.x, g = blockIdx.x;
    int w = tid >> 6, lane = tid & 63;
    int quad = lane >> 4, l15 = lane & 15;

    auxA[tid]       = scale[tid];
    auxA[256 + tid] = shift[tid];
    b2l[tid] = b2[tid];
    w2t[tid] = w2tw[tid];
    __syncthreads();

    // Phase A: iteration ii covers rows w*16 + ii*4 + quad; lane covers cols
    // [l15*16, l15*16+16). Score reduce across l15 only (4 shfls / 4 rows).
#pragma unroll
    for (int ii = 0; ii < 4; ++ii) {
        int row = w * 16 + ii * 4 + quad;
        const uint* hrow = h1p + (size_t)(g * 64 + row) * 256 + l15 * 16;
        float pr = 0.f;
        ushort hvv[16];
#pragma unroll
        for (int j = 0; j < 4; ++j) {
            uint4 u = *(const uint4*)(hrow + 4 * j);
            float4 sc4 = *(const float4*)(&auxA[l15 * 16 + 4 * j]);
            float4 sh4 = *(const float4*)(&auxA[256 + l15 * 16 + 4 * j]);
            float4 wt4 = *(const float4*)(&w2t[l15 * 16 + 4 * j]);
            uint us[4] = {u.x, u.y, u.z, u.w};
            float scs[4] = {sc4.x, sc4.y, sc4.z, sc4.w};
            float shs[4] = {sh4.x, sh4.y, sh4.z, sh4.w};
            float wts[4] = {wt4.x, wt4.y, wt4.z, wt4.w};
#pragma unroll
            for (int e = 0; e < 4; ++e) {
                float v = bf2f((ushort)(us[e] & 0xffffu)) + bf2f((ushort)(us[e] >> 16));
                float t = fmaxf(v * scs[e] + shs[e], 0.f);
                pr += t * wts[e];
                hvv[4 * j + e] = f2bf(t);
            }
        }
        uint o[8];
#pragma unroll
        for (int q2 = 0; q2 < 8; ++q2)
            o[q2] = (uint)hvv[2 * q2] | ((uint)hvv[2 * q2 + 1] << 16);
        uint4 o0; o0.x = o[0]; o0.y = o[1]; o0.z = o[2]; o0.w = o[3];
        uint4 o1; o1.x = o[4]; o1.y = o[5]; o1.z = o[6]; o1.w = o[7];
        *(uint4*)(&hhi[row * 264 + l15 * 16])     = o0;
        *(uint4*)(&hhi[row * 264 + l15 * 16 + 8]) = o1;
        pr += __shfl_xor(pr, 1, 64);
        pr += __shfl_xor(pr, 2, 64);
        pr += __shfl_xor(pr, 4, 64);
        pr += __shfl_xor(pr, 8, 64);
        if (l15 == 0) slds[row] = pr;
    }
    __syncthreads();

    const float invn = scalars[0], b2tw = scalars[1];
    if (tid < 64) {
        float s = slds[tid];
        int rank = 0;
        for (int j2 = 0; j2 < 64; ++j2) {
            float sj = slds[j2];
            rank += (sj > s) || (sj == s && j2 < tid);
        }
        int issel = rank < KSEL;
        sel[tid]  = issel;
        gate[tid] = issel ? tanhf((s + b2tw) * invn) : 0.f;
    }
    __syncthreads();

    // GEMM2 + fused pooling
    {
        float gr[4][4]; int sr[4][4];
#pragma unroll
        for (int p = 0; p < 4; ++p)
#pragma unroll
            for (int r = 0; r < 4; ++r) {
                int row = p * 16 + quad * 4 + r;
                gr[p][r] = gate[row]; sr[p][r] = sel[row];
            }
        float lmax[4] = {-1.0e30f, -1.0e30f, -1.0e30f, -1.0e30f};
        float lsum[4] = {0.f, 0.f, 0.f, 0.f};
#pragma unroll
        for (int nt = 0; nt < 4; ++nt) {
            int ntg = w * 4 + nt;
            frag_cd acc[4];
#pragma unroll
            for (int p = 0; p < 4; ++p) acc[p] = (frag_cd){0.f, 0.f, 0.f, 0.f};
#pragma unroll
            for (int kt = 0; kt < 8; ++kt) {
                frag_ab bh = *(const frag_ab*)(w2h + ((kt * 16 + ntg) * 64 + lane) * 8);
#pragma unroll
                for (int p = 0; p < 4; ++p) {
                    int offa = (p * 16 + l15) * 264 + kt * 32 + quad * 8;
                    frag_ab a2h = *(const frag_ab*)(hhi + offa);
                    acc[p] = __builtin_amdgcn_mfma_f32_16x16x32_bf16(a2h, bh, acc[p], 0, 0, 0);
                }
            }
            int c = ntg * 16 + l15;
            float bias = b2l[c];
#pragma unroll
            for (int p = 0; p < 4; ++p)
#pragma unroll
                for (int r = 0; r < 4; ++r) {
                    if (sr[p][r]) {
                        float v = (acc[p][r] + bias) * gr[p][r];
                        lsum[nt] += v;
                        lmax[nt] = fmaxf(lmax[nt], v);
                    }
                }
        }
#pragma unroll
        for (int nt = 0; nt < 4; ++nt) {
            lsum[nt] += __shfl_xor(lsum[nt], 16, 64);
            lsum[nt] += __shfl_xor(lsum[nt], 32, 64);
            lmax[nt] = fmaxf(lmax[nt], __shfl_xor(lmax[nt], 16, 64));
            lmax[nt] = fmaxf(lmax[nt], __shfl_xor(lmax[nt], 32, 64));
        }
        __syncthreads();
        if (quad == 0) {
#pragma unroll
            for (int nt = 0; nt < 4; ++nt) {
                int c = (w * 4 + nt) * 16 + l15;
                auxA[c]       = lmax[nt];
                auxA[256 + c] = lsum[nt] * (1.0f / 52.0f);
            }
        }
    }
    __syncthreads();

    // FC via transposed weights: coalesced dword loads, cat broadcast from LDS
    {
        float a0 = 0.f, a1 = 0.f, a2 = 0.f, a3 = 0.f;
#pragma unroll 4
        for (int k = 0; k < 512; k += 4) {
            a0 += fcwT[(size_t)(k + 0) * 256 + tid] * auxA[k + 0];
            a1 += fcwT[(size_t)(k + 1) * 256 + tid] * auxA[k + 1];
            a2 += fcwT[(size_t)(k + 2) * 256 + tid] * auxA[k + 2];
            a3 += fcwT[(size_t)(k + 3) * 256 + tid] * auxA[k + 3];
        }
        out[(size_t)g * 256 + tid] = fcb[tid] + ((a0 + a1) + (a2 + a3));
    }
}

// ---------------------------------------------------------------------------
extern "C" void kernel_launch(void* const* d_in, const int* in_sizes, int n_in,
                              void* d_out, int out_size, void* d_ws, size_t ws_size,
                              hipStream_t stream) {
    const int*   tokens = (const int*)d_in[0];
    const int*   ntype  = (const int*)d_in[1];
    const int*   eidx   = (const int*)d_in[2];
    const float* st     = (const float*)d_in[3];
    const float* nte    = (const float*)d_in[4];
    const float* W1     = (const float*)d_in[5];
    const float* b1     = (const float*)d_in[6];
    const float* gam    = (const float*)d_in[7];
    const float* bet    = (const float*)d_in[8];
    const float* W2     = (const float*)d_in[9];
    const float* b2     = (const float*)d_in[10];
    const float* tw     = (const float*)d_in[11];
    const float* fcw    = (const float*)d_in[12];
    const float* fcb    = (const float*)d_in[13];

    // shared small block (base of ws)
    char* ws = (char*)d_ws;
    ushort* w1h     = (ushort*)(ws);                 // 64 KB
    ushort* w1l     = (ushort*)(ws + 65536);         // 64 KB
    ushort* w2h     = (ushort*)(ws + 131072);        // 128 KB
    ushort* w2l     = (ushort*)(ws + 262144);        // 128 KB
    float*  scale   = (float*)(ws + 393216);         // 1 KB
    float*  shift   = (float*)(ws + 394240);         // 1 KB
    float*  scalars = (float*)(ws + 395264);         // 256 B
    float*  w2tw    = (float*)(ws + 395520);         // 1 KB
    float*  partial = (float*)(ws + 396544);         // 4 MB -> ends 4,590,848
    float*  fcwT    = partial;                       // 512 KB, reuses partial after k_stats
    char*   big     = ws + 4590848;

    const int* esrc = eidx;
    const int* edst = eidx + 524288;

    k_setup<<<385, 256, 0, stream>>>(W1, W2, tw, b2, w1h, w1l, w2h, w2l, scalars, w2tw);

    if (ws_size >= 4590848ull + 134217728ull) {
        // MAIN path: h1 (acc+b1) stored packed hi|lo bf16, 128 MB
        uint* h1p = (uint*)big;
        k_conv2<<<2048, 256, 0, stream>>>(tokens, ntype, st, nte, esrc, edst,
                                          w1h, w1l, b1, h1p, partial);
        k_stats<<<256,  256, 0, stream>>>(partial, gam, bet, scale, shift);
        k_prep2<<<512,  256, 0, stream>>>(fcw, fcwT);   // partial is dead now
        k_final2<<<2048, 256, 0, stream>>>(h1p, w2h, b2, scale, shift, scalars,
                                           w2tw, fcwT, fcb, (float*)d_out);
    } else {
        // FALLBACK path: h0 hi/lo planes, GEMM1 recompute in k_final
        ushort* h0hi = (ushort*)big;
        ushort* h0lo = (ushort*)(big + 33554432);
        k_conv <<<2048, 256, 0, stream>>>(tokens, ntype, st, nte, esrc, edst,
                                          w1h, w1l, b1, h0hi, h0lo, partial);
        k_stats<<<256,  256, 0, stream>>>(partial, gam, bet, scale, shift);
        k_prep2<<<512,  256, 0, stream>>>(fcw, fcwT);
        k_final<<<2048, 256, 0, stream>>>(h0hi, h0lo, w1h, w1l, w2h, b1, b2,
                                          scale, shift, scalars, w2tw, fcwT, fcb, (float*)d_out);
    }
}